// Round 1
// baseline (68.550 us; speedup 1.0000x reference)
//
#include <hip/hip_runtime.h>
#include <math.h>

// Diversity8: loss = mean_b( 0.3 * 0.5 * sum_{m!=n} corr(p_m[b], p_n[b]) )
// p_m = softmax(x_m / 20) per row of C=1000 classes, M=8 models.
// corr via centered unit-normalized rows; diagonal cancelled algebraically.

constexpr int BLOCK = 256;
constexpr int NC    = 1000;
constexpr int NC4   = 250;   // float4 chunks per row
constexpr int NM    = 8;
constexpr float TINV = 1.0f / 20.0f;
constexpr float INVC = 1.0f / (float)NC;

__device__ __forceinline__ float waveMax(float v) {
#pragma unroll
    for (int o = 32; o > 0; o >>= 1) v = fmaxf(v, __shfl_xor(v, o, 64));
    return v;
}
__device__ __forceinline__ float waveSum(float v) {
#pragma unroll
    for (int o = 32; o > 0; o >>= 1) v += __shfl_xor(v, o, 64);
    return v;
}
__device__ __forceinline__ double waveSumD(double v) {
#pragma unroll
    for (int o = 32; o > 0; o >>= 1) v += __shfl_xor(v, o, 64);
    return v;
}

__global__ __launch_bounds__(BLOCK) void div8_main(
    const float* __restrict__ in0, const float* __restrict__ in1,
    const float* __restrict__ in2, const float* __restrict__ in3,
    const float* __restrict__ in4, const float* __restrict__ in5,
    const float* __restrict__ in6, const float* __restrict__ in7,
    float* __restrict__ part)
{
    const int b    = blockIdx.x;
    const int t    = threadIdx.x;
    const int lane = t & 63;
    const int wid  = t >> 6;

    __shared__ float  eLDS[NM][NC];   // exp tile, 32000 B (rows 16B-aligned: 4000B each)
    __shared__ float  red[4];
    __shared__ float  red8[4][NM];
    __shared__ double redd[4];

    const float* rows[NM] = {
        in0 + (size_t)b * NC, in1 + (size_t)b * NC,
        in2 + (size_t)b * NC, in3 + (size_t)b * NC,
        in4 + (size_t)b * NC, in5 + (size_t)b * NC,
        in6 + (size_t)b * NC, in7 + (size_t)b * NC };

    float invSm[NM];

    // ---- per-model: max, exp, sum(exp); stash exp in LDS ----
#pragma unroll
    for (int m = 0; m < NM; ++m) {
        float4 x;
        float mloc = -INFINITY;
        if (t < NC4) {
            x = reinterpret_cast<const float4*>(rows[m])[t];
            x.x *= TINV; x.y *= TINV; x.z *= TINV; x.w *= TINV;
            mloc = fmaxf(fmaxf(x.x, x.y), fmaxf(x.z, x.w));
        }
        float wm = waveMax(mloc);
        if (lane == 0) red[wid] = wm;
        __syncthreads();
        const float mx = fmaxf(fmaxf(red[0], red[1]), fmaxf(red[2], red[3]));
        __syncthreads();  // protect red before reuse

        float sloc = 0.f;
        if (t < NC4) {
            float e0 = __expf(x.x - mx);
            float e1 = __expf(x.y - mx);
            float e2 = __expf(x.z - mx);
            float e3 = __expf(x.w - mx);
            reinterpret_cast<float4*>(&eLDS[m][0])[t] = make_float4(e0, e1, e2, e3);
            sloc = (e0 + e1) + (e2 + e3);
        }
        float ws_ = waveSum(sloc);
        if (lane == 0) red[wid] = ws_;
        __syncthreads();
        const float S = (red[0] + red[1]) + (red[2] + red[3]);
        invSm[m] = 1.0f / S;
        __syncthreads();  // red reuse next iter; eLDS[m] now visible
    }

    // ---- pass 2: q_m = sum_c (p - 1/C)^2  (no cancellation) ----
    float q[NM];
#pragma unroll
    for (int m = 0; m < NM; ++m) q[m] = 0.f;
    for (int c = t; c < NC; c += BLOCK) {
#pragma unroll
        for (int m = 0; m < NM; ++m) {
            float u = fmaf(eLDS[m][c], invSm[m], -INVC);
            q[m] = fmaf(u, u, q[m]);
        }
    }
#pragma unroll
    for (int m = 0; m < NM; ++m) {
        float r = waveSum(q[m]);
        if (lane == 0) red8[wid][m] = r;
    }
    __syncthreads();
    float am[NM], bm[NM];
#pragma unroll
    for (int m = 0; m < NM; ++m) {
        float qt = (red8[0][m] + red8[1][m]) + (red8[2][m] + red8[3][m]);
        float rm = 1.0f / sqrtf(qt);     // w = u * rm is unit-norm
        am[m] = invSm[m] * rm;
        bm[m] = -INVC * rm;
    }

    // ---- pass 3: cross = sum_c [ (sum_m w)^2 - sum_m w^2 ] ----
    double cr = 0.0;
    for (int c = t; c < NC; c += BLOCK) {
        float tsum = 0.f, sw2 = 0.f;
#pragma unroll
        for (int m = 0; m < NM; ++m) {
            float w = fmaf(eLDS[m][c], am[m], bm[m]);
            tsum += w;
            sw2 = fmaf(w, w, sw2);
        }
        cr += (double)fmaf(tsum, tsum, -sw2);  // single rounding for t^2 - sw2
    }
    double cw = waveSumD(cr);
    if (lane == 0) redd[wid] = cw;
    __syncthreads();
    if (t == 0) {
        double tot = (redd[0] + redd[1]) + (redd[2] + redd[3]);
        part[b] = (float)tot;   // = sum_{m!=n} G_mn for sample b
    }
}

__global__ __launch_bounds__(BLOCK) void div8_final(
    const float* __restrict__ part, float* __restrict__ out, int B)
{
    const int t = threadIdx.x;
    double acc = 0.0;
    for (int i = t; i < B; i += BLOCK) acc += (double)part[i];  // fixed order: deterministic
    acc = waveSumD(acc);
    __shared__ double redd[4];
    if ((t & 63) == 0) redd[t >> 6] = acc;
    __syncthreads();
    if (t == 0) {
        double tot = (redd[0] + redd[1]) + (redd[2] + redd[3]);
        // loss = mean( 0.3 * 0.5 * cross_b )
        out[0] = (float)(tot * (0.5 * 0.3 / (double)B));
    }
}

extern "C" void kernel_launch(void* const* d_in, const int* in_sizes, int n_in,
                              void* d_out, int out_size, void* d_ws, size_t ws_size,
                              hipStream_t stream)
{
    const float* a0 = (const float*)d_in[0];
    const float* a1 = (const float*)d_in[1];
    const float* a2 = (const float*)d_in[2];
    const float* a3 = (const float*)d_in[3];
    const float* a4 = (const float*)d_in[4];
    const float* a5 = (const float*)d_in[5];
    const float* a6 = (const float*)d_in[6];
    const float* a7 = (const float*)d_in[7];
    const int B = in_sizes[0] / NC;   // 4096

    float* part = (float*)d_ws;       // B floats of scratch

    div8_main<<<B, BLOCK, 0, stream>>>(a0, a1, a2, a3, a4, a5, a6, a7, part);
    div8_final<<<1, BLOCK, 0, stream>>>(part, (float*)d_out, B);
}

// Round 2
// 58.015 us; speedup vs baseline: 1.1816x; 1.1816x over previous
//
#include <hip/hip_runtime.h>
#include <math.h>

// Diversity8: loss = mean_b( 0.3 * 0.5 * sum_{m!=n} corr(p_m[b], p_n[b]) )
// p_m = softmax(x_m / 20) per row of C=1000 classes, M=8 models.
// All-register version: thread t owns classes [4t..4t+3] of all 8 models.
// No LDS data tile; 6 barrier rounds per block instead of ~26.

constexpr int BLOCK = 256;
constexpr int NC    = 1000;
constexpr int NC4   = 250;   // float4 chunks per row
constexpr int NM    = 8;
constexpr float TINV = 1.0f / 20.0f;
constexpr float INVC = 1.0f / (float)NC;

__device__ __forceinline__ float waveMax(float v) {
#pragma unroll
    for (int o = 32; o > 0; o >>= 1) v = fmaxf(v, __shfl_xor(v, o, 64));
    return v;
}
__device__ __forceinline__ float waveSum(float v) {
#pragma unroll
    for (int o = 32; o > 0; o >>= 1) v += __shfl_xor(v, o, 64);
    return v;
}
__device__ __forceinline__ double waveSumD(double v) {
#pragma unroll
    for (int o = 32; o > 0; o >>= 1) v += __shfl_xor(v, o, 64);
    return v;
}

__global__ __launch_bounds__(BLOCK) void div8_main(
    const float* __restrict__ in0, const float* __restrict__ in1,
    const float* __restrict__ in2, const float* __restrict__ in3,
    const float* __restrict__ in4, const float* __restrict__ in5,
    const float* __restrict__ in6, const float* __restrict__ in7,
    float* __restrict__ part)
{
    const int b    = blockIdx.x;
    const int t    = threadIdx.x;
    const int lane = t & 63;
    const int wid  = t >> 6;
    const bool act = (t < NC4);

    __shared__ float  red8[4][NM];   // per-wave partials, broadcast-read
    __shared__ double redd[4];

    const float* rows[NM] = {
        in0 + (size_t)b * NC, in1 + (size_t)b * NC,
        in2 + (size_t)b * NC, in3 + (size_t)b * NC,
        in4 + (size_t)b * NC, in5 + (size_t)b * NC,
        in6 + (size_t)b * NC, in7 + (size_t)b * NC };

    // ---- issue ALL 8 loads before any reduction (latency overlap) ----
    float4 x[NM];
#pragma unroll
    for (int m = 0; m < NM; ++m) {
        x[m] = act ? reinterpret_cast<const float4*>(rows[m])[t]
                   : make_float4(0.f, 0.f, 0.f, 0.f);
    }

    // ---- scale + per-thread max; batch all 8 max-reductions in 1 barrier ----
#pragma unroll
    for (int m = 0; m < NM; ++m) {
        x[m].x *= TINV; x[m].y *= TINV; x[m].z *= TINV; x[m].w *= TINV;
        float mloc = act ? fmaxf(fmaxf(x[m].x, x[m].y), fmaxf(x[m].z, x[m].w))
                         : -INFINITY;
        mloc = waveMax(mloc);
        if (lane == 0) red8[wid][m] = mloc;
    }
    __syncthreads();
    float mx[NM];
#pragma unroll
    for (int m = 0; m < NM; ++m)
        mx[m] = fmaxf(fmaxf(red8[0][m], red8[1][m]), fmaxf(red8[2][m], red8[3][m]));
    __syncthreads();   // red8 reused below

    // ---- exp in-place; batch all 8 sum-reductions in 1 barrier ----
#pragma unroll
    for (int m = 0; m < NM; ++m) {
        x[m].x = __expf(x[m].x - mx[m]);
        x[m].y = __expf(x[m].y - mx[m]);
        x[m].z = __expf(x[m].z - mx[m]);
        x[m].w = __expf(x[m].w - mx[m]);
        float s = act ? (x[m].x + x[m].y) + (x[m].z + x[m].w) : 0.f;
        s = waveSum(s);
        if (lane == 0) red8[wid][m] = s;
    }
    __syncthreads();
    float invSm[NM];
#pragma unroll
    for (int m = 0; m < NM; ++m) {
        float S = (red8[0][m] + red8[1][m]) + (red8[2][m] + red8[3][m]);
        invSm[m] = 1.0f / S;
    }
    __syncthreads();   // red8 reused below

    // ---- q_m = sum_c (p - 1/C)^2 ; batch reduce ----
#pragma unroll
    for (int m = 0; m < NM; ++m) {
        float qq = 0.f;
        if (act) {
            float u0 = fmaf(x[m].x, invSm[m], -INVC);
            float u1 = fmaf(x[m].y, invSm[m], -INVC);
            float u2 = fmaf(x[m].z, invSm[m], -INVC);
            float u3 = fmaf(x[m].w, invSm[m], -INVC);
            qq = fmaf(u0, u0, fmaf(u1, u1, fmaf(u2, u2, u3 * u3)));
        }
        qq = waveSum(qq);
        if (lane == 0) red8[wid][m] = qq;
    }
    __syncthreads();
    float am[NM], bm[NM];
#pragma unroll
    for (int m = 0; m < NM; ++m) {
        float qt = (red8[0][m] + red8[1][m]) + (red8[2][m] + red8[3][m]);
        float rm = 1.0f / sqrtf(qt);     // w = u * rm is unit-norm
        am[m] = invSm[m] * rm;
        bm[m] = -INVC * rm;
    }

    // ---- cross = sum_c [ (sum_m w)^2 - sum_m w^2 ] ----
    double cr = 0.0;
    if (act) {
#pragma unroll
        for (int j = 0; j < 4; ++j) {
            float tsum = 0.f, sw2 = 0.f;
#pragma unroll
            for (int m = 0; m < NM; ++m) {
                float e = (j == 0) ? x[m].x : (j == 1) ? x[m].y : (j == 2) ? x[m].z : x[m].w;
                float w = fmaf(e, am[m], bm[m]);
                tsum += w;
                sw2 = fmaf(w, w, sw2);
            }
            cr += (double)fmaf(tsum, tsum, -sw2);  // single rounding for t^2 - sw2
        }
    }
    cr = waveSumD(cr);
    if (lane == 0) redd[wid] = cr;
    __syncthreads();
    if (t == 0) {
        double tot = (redd[0] + redd[1]) + (redd[2] + redd[3]);
        part[b] = (float)tot;   // = sum_{m!=n} G_mn for sample b
    }
}

__global__ __launch_bounds__(BLOCK) void div8_final(
    const float* __restrict__ part, float* __restrict__ out, int B)
{
    const int t = threadIdx.x;
    double acc = 0.0;
    for (int i = t; i < B; i += BLOCK) acc += (double)part[i];  // fixed order: deterministic
    acc = waveSumD(acc);
    __shared__ double redd[4];
    if ((t & 63) == 0) redd[t >> 6] = acc;
    __syncthreads();
    if (t == 0) {
        double tot = (redd[0] + redd[1]) + (redd[2] + redd[3]);
        // loss = mean( 0.3 * 0.5 * cross_b )
        out[0] = (float)(tot * (0.5 * 0.3 / (double)B));
    }
}

extern "C" void kernel_launch(void* const* d_in, const int* in_sizes, int n_in,
                              void* d_out, int out_size, void* d_ws, size_t ws_size,
                              hipStream_t stream)
{
    const float* a0 = (const float*)d_in[0];
    const float* a1 = (const float*)d_in[1];
    const float* a2 = (const float*)d_in[2];
    const float* a3 = (const float*)d_in[3];
    const float* a4 = (const float*)d_in[4];
    const float* a5 = (const float*)d_in[5];
    const float* a6 = (const float*)d_in[6];
    const float* a7 = (const float*)d_in[7];
    const int B = in_sizes[0] / NC;   // 4096

    float* part = (float*)d_ws;       // B floats of scratch

    div8_main<<<B, BLOCK, 0, stream>>>(a0, a1, a2, a3, a4, a5, a6, a7, part);
    div8_final<<<1, BLOCK, 0, stream>>>(part, (float*)d_out, B);
}

// Round 3
// 35.978 us; speedup vs baseline: 1.9054x; 1.6125x over previous
//
#include <hip/hip_runtime.h>
#include <math.h>

// Diversity8: loss = mean_b( 0.3 * 0.5 * sum_{m!=n} corr(p_m[b], p_n[b]) )
// One WAVE per sample: no LDS, no __syncthreads, all reductions via shfl_xor.
// Lane l owns float4 chunks {l, l+64, l+128, l+192} of each of the 8 rows.

constexpr int NC   = 1000;
constexpr int NC4  = 250;     // float4 chunks per row
constexpr int NM   = 8;
constexpr float TINV = 1.0f / 20.0f;
constexpr float INVC = 1.0f / (float)NC;

__device__ __forceinline__ float waveMax(float v) {
#pragma unroll
    for (int o = 32; o > 0; o >>= 1) v = fmaxf(v, __shfl_xor(v, o, 64));
    return v;
}
__device__ __forceinline__ float waveSum(float v) {
#pragma unroll
    for (int o = 32; o > 0; o >>= 1) v += __shfl_xor(v, o, 64);
    return v;
}
__device__ __forceinline__ double waveSumD(double v) {
#pragma unroll
    for (int o = 32; o > 0; o >>= 1) v += __shfl_xor(v, o, 64);
    return v;
}

__global__ __launch_bounds__(64, 2) void div8_main(
    const float* __restrict__ in0, const float* __restrict__ in1,
    const float* __restrict__ in2, const float* __restrict__ in3,
    const float* __restrict__ in4, const float* __restrict__ in5,
    const float* __restrict__ in6, const float* __restrict__ in7,
    float* __restrict__ part)
{
    const int b    = blockIdx.x;
    const int lane = threadIdx.x;            // 0..63, one wave
    const bool act3 = lane < (NC4 - 3 * 64); // lane < 58: chunk j=3 valid

    const float* rows[NM] = {
        in0 + (size_t)b * NC, in1 + (size_t)b * NC,
        in2 + (size_t)b * NC, in3 + (size_t)b * NC,
        in4 + (size_t)b * NC, in5 + (size_t)b * NC,
        in6 + (size_t)b * NC, in7 + (size_t)b * NC };

    // ---- issue ALL 32 loads up front (coalesced: consecutive lanes,
    //      consecutive float4) ----
    float4 x[NM][4];
#pragma unroll
    for (int m = 0; m < NM; ++m) {
        const float4* p = reinterpret_cast<const float4*>(rows[m]);
#pragma unroll
        for (int j = 0; j < 4; ++j) {
            if (j < 3)
                x[m][j] = p[lane + 64 * j];
            else
                x[m][j] = act3 ? p[lane + 192]
                               : make_float4(-INFINITY, -INFINITY, -INFINITY, -INFINITY);
        }
    }

    // ---- per-model max of raw logits (pads are -inf: harmless) ----
    float mxs[NM];
#pragma unroll
    for (int m = 0; m < NM; ++m) {
        float v = fmaxf(fmaxf(x[m][0].x, x[m][0].y), fmaxf(x[m][0].z, x[m][0].w));
#pragma unroll
        for (int j = 1; j < 4; ++j)
            v = fmaxf(v, fmaxf(fmaxf(x[m][j].x, x[m][j].y),
                               fmaxf(x[m][j].z, x[m][j].w)));
        mxs[m] = waveMax(v) * TINV;   // max of x/T
    }

    // ---- exp in-place + sum(exp); pads give exp(-inf)=0 ----
    float invS[NM];
#pragma unroll
    for (int m = 0; m < NM; ++m) {
        float s = 0.f;
#pragma unroll
        for (int j = 0; j < 4; ++j) {
            x[m][j].x = __expf(fmaf(x[m][j].x, TINV, -mxs[m]));
            x[m][j].y = __expf(fmaf(x[m][j].y, TINV, -mxs[m]));
            x[m][j].z = __expf(fmaf(x[m][j].z, TINV, -mxs[m]));
            x[m][j].w = __expf(fmaf(x[m][j].w, TINV, -mxs[m]));
            s += (x[m][j].x + x[m][j].y) + (x[m][j].z + x[m][j].w);
        }
        invS[m] = 1.0f / waveSum(s);
    }

    // ---- q_m = sum_c (p - 1/C)^2  (cancellation-free) ----
    float am[NM], bm[NM];
#pragma unroll
    for (int m = 0; m < NM; ++m) {
        float qq = 0.f;
#pragma unroll
        for (int j = 0; j < 4; ++j) {
            if (j == 3 && !act3) continue;  // pads would wrongly add INVC^2
            float u0 = fmaf(x[m][j].x, invS[m], -INVC);
            float u1 = fmaf(x[m][j].y, invS[m], -INVC);
            float u2 = fmaf(x[m][j].z, invS[m], -INVC);
            float u3 = fmaf(x[m][j].w, invS[m], -INVC);
            qq = fmaf(u0, u0, fmaf(u1, u1, fmaf(u2, u2, fmaf(u3, u3, qq))));
        }
        float qt = waveSum(qq);
        float rm = 1.0f / sqrtf(qt);   // w = u * rm is unit-norm
        am[m] = invS[m] * rm;
        bm[m] = -INVC * rm;
    }

    // ---- cross = sum_c [ (sum_m w)^2 - sum_m w^2 ] ----
    double cr = 0.0;
#pragma unroll
    for (int j = 0; j < 4; ++j) {
        if (j == 3 && !act3) continue;
        float tx = 0.f, ty = 0.f, tz = 0.f, tw = 0.f;
        float sx = 0.f, sy = 0.f, sz = 0.f, sw = 0.f;
#pragma unroll
        for (int m = 0; m < NM; ++m) {
            float wx_ = fmaf(x[m][j].x, am[m], bm[m]); tx += wx_; sx = fmaf(wx_, wx_, sx);
            float wy_ = fmaf(x[m][j].y, am[m], bm[m]); ty += wy_; sy = fmaf(wy_, wy_, sy);
            float wz_ = fmaf(x[m][j].z, am[m], bm[m]); tz += wz_; sz = fmaf(wz_, wz_, sz);
            float ww_ = fmaf(x[m][j].w, am[m], bm[m]); tw += ww_; sw = fmaf(ww_, ww_, sw);
        }
        cr += (double)fmaf(tx, tx, -sx);
        cr += (double)fmaf(ty, ty, -sy);
        cr += (double)fmaf(tz, tz, -sz);
        cr += (double)fmaf(tw, tw, -sw);
    }
    cr = waveSumD(cr);
    if (lane == 0) part[b] = (float)cr;   // = sum_{m!=n} G_mn for sample b
}

__global__ __launch_bounds__(256) void div8_final(
    const float* __restrict__ part, float* __restrict__ out, int B)
{
    const int t = threadIdx.x;
    double acc = 0.0;
    for (int i = t; i < B; i += 256) acc += (double)part[i];  // fixed order: deterministic
    acc = waveSumD(acc);
    __shared__ double redd[4];
    if ((t & 63) == 0) redd[t >> 6] = acc;
    __syncthreads();
    if (t == 0) {
        double tot = (redd[0] + redd[1]) + (redd[2] + redd[3]);
        // loss = mean( 0.3 * 0.5 * cross_b )
        out[0] = (float)(tot * (0.5 * 0.3 / (double)B));
    }
}

extern "C" void kernel_launch(void* const* d_in, const int* in_sizes, int n_in,
                              void* d_out, int out_size, void* d_ws, size_t ws_size,
                              hipStream_t stream)
{
    const float* a0 = (const float*)d_in[0];
    const float* a1 = (const float*)d_in[1];
    const float* a2 = (const float*)d_in[2];
    const float* a3 = (const float*)d_in[3];
    const float* a4 = (const float*)d_in[4];
    const float* a5 = (const float*)d_in[5];
    const float* a6 = (const float*)d_in[6];
    const float* a7 = (const float*)d_in[7];
    const int B = in_sizes[0] / NC;   // 4096

    float* part = (float*)d_ws;       // B floats of scratch

    div8_main<<<B, 64, 0, stream>>>(a0, a1, a2, a3, a4, a5, a6, a7, part);
    div8_final<<<1, 256, 0, stream>>>(part, (float*)d_out, B);
}